// Round 15
// baseline (188.868 us; speedup 1.0000x reference)
//
#include <hip/hip_runtime.h>
#include <hip/hip_bf16.h>

typedef __bf16 bf16;
typedef __attribute__((ext_vector_type(8))) __bf16 bf16x8;
typedef __attribute__((ext_vector_type(4))) __bf16 bf16x4;
typedef __attribute__((ext_vector_type(4))) float f32x4;
typedef __attribute__((ext_vector_type(4))) unsigned int uint4x;

#if __has_builtin(__builtin_amdgcn_exp2f)
#define EXP2F(x) __builtin_amdgcn_exp2f(x)
#else
#define EXP2F(x) exp2f(x)
#endif

#define AS1 __attribute__((address_space(1)))
#define AS3 __attribute__((address_space(3)))

static __device__ __forceinline__ void async_ld16(const bf16* g, bf16* l) {
  __builtin_amdgcn_global_load_lds((const AS1 void*)g, (AS3 void*)l, 16, 0, 0);
}

// f32 -> bf16 with EXPLICIT round-to-nearest-even bit arithmetic (proven in
// round 4: cvt_pk-based paths failed at ~9e-3; this passes at 2.4e-3).
// Valid for positive finite inputs (exp2 output); no NaN handling needed.
static __device__ __forceinline__ unsigned bf16rne(float x) {
  unsigned u = __float_as_uint(x);
  return (u + 0x7fffu + ((u >> 16) & 1u)) >> 16;
}
static __device__ __forceinline__ unsigned pack2(float a, float b) {
  return bf16rne(a) | (bf16rne(b) << 16);
}

// ---------------- fused fp32 -> bf16 conversion (x, qkv_w, fc_w) ----------
__global__ void cvt3_kernel(const float* __restrict__ x, const float* __restrict__ qw,
                            const float* __restrict__ fw, bf16* __restrict__ xb,
                            bf16* __restrict__ qwb, bf16* __restrict__ fwb) {
  int b = blockIdx.x;
  const float* src;
  bf16* dst;
  int i;
  if (b < 4096) { src = x; dst = xb; i = b * 256 + threadIdx.x; }
  else if (b < 7168) { src = qw; dst = qwb; i = (b - 4096) * 256 + threadIdx.x; }
  else { src = fw; dst = fwb; i = (b - 7168) * 256 + threadIdx.x; }
  f32x4 v = *(const f32x4*)(src + (size_t)i * 4);
  bf16x4 o;
  o[0] = (bf16)v[0]; o[1] = (bf16)v[1]; o[2] = (bf16)v[2]; o[3] = (bf16)v[3];
  *(bf16x4*)(dst + (size_t)i * 4) = o;
}

// ---------------- BT-GEMM: C[M,N] = A[M,K] @ B[N,K]^T ----------------
// (byte-identical to the passing rounds 13/14: T4 counted-vmcnt + raw
// s_barrier distance-2 K-loop, T2 pre-swizzled-source XOR fragment reads.)
// MODE 0 epilogue: bias + head_mask; Q -> [nh][s][d] (x log2(e)/8);
//   K -> fragment-major Kf with the LANE-LOCAL-P permutation baked in
//     (key g at C-tile ct = 2*(g>>5)+((g>>2)&1), row i = ((g>>3)&3)*4+(g&3));
//   V -> natural fragment-major Vf. Both key-linear at 32-key granularity.
// MODE 1: fp32 out = acc + bias.
#define GEMM_STAGE(k0_, buf_)                                                    \
  {                                                                              \
    async_ld16(A + (size_t)(rowBase + r0) * Kdim + (k0_) + csw, &As[buf_][f0]);  \
    async_ld16(A + (size_t)(rowBase + r1) * Kdim + (k0_) + csw, &As[buf_][f1]);  \
    async_ld16(Bw + (size_t)(colBase + r0) * Kdim + (k0_) + csw, &Bs[buf_][f0]); \
    async_ld16(Bw + (size_t)(colBase + r1) * Kdim + (k0_) + csw, &Bs[buf_][f1]); \
  }

template <int MODE>
__global__ __launch_bounds__(256, 2) void gemm_bt_kernel(
    const bf16* __restrict__ A, const bf16* __restrict__ Bw,
    const float* __restrict__ bias, const float* __restrict__ hm,
    bf16* __restrict__ Qp, bf16* __restrict__ Kp, bf16* __restrict__ Vp,
    float* __restrict__ outF, int Ncols, int Kdim, int rowBlkCount) {
  __shared__ bf16 As[2][128 * 32];
  __shared__ bf16 Bs[2][128 * 32];
  const int t = threadIdx.x, lane = t & 63, w = t >> 6;
  const int wr = w >> 1, wc = w & 1;
  const int j = lane & 15, quad = lane >> 4;
  const int rowBlk = blockIdx.x % rowBlkCount;
  const int colBlk = blockIdx.x / rowBlkCount;
  const int rowBase = rowBlk * 128, colBase = colBlk * 128;

  f32x4 acc[4][4];
  const f32x4 z4 = {0.f, 0.f, 0.f, 0.f};
#pragma unroll
  for (int i = 0; i < 4; ++i)
#pragma unroll
    for (int jj = 0; jj < 4; ++jj) acc[i][jj] = z4;

  const int f0 = t * 8;
  const int f1 = f0 + 2048;
  const int r0 = f0 >> 5, r1 = r0 + 64;
  const int csw = (((t & 3) ^ ((r0 >> 1) & 3))) * 8;
  const int qsw = (quad ^ ((j >> 1) & 3)) * 8;

  // distance-2 prologue: tiles 0 and 1 in flight (8 loads/thread)
  GEMM_STAGE(0, 0);
  if (32 < Kdim) GEMM_STAGE(32, 1);
  int buf = 0;
  for (int k0 = 0; k0 < Kdim; k0 += 32) {
    // wait only THIS tile's 4 loads (oldest); next tile's stay in flight
    if (k0 + 32 < Kdim) {
      asm volatile("s_waitcnt vmcnt(4)" ::: "memory");
    } else {
      asm volatile("s_waitcnt vmcnt(0)" ::: "memory");
    }
    __builtin_amdgcn_s_barrier();        // all waves' tile loads complete
    __builtin_amdgcn_sched_barrier(0);   // rule #18: pin ds_reads after wait
    bf16x8 af[4], bfr[4];
#pragma unroll
    for (int i = 0; i < 4; ++i)
      af[i] = *(const bf16x8*)&As[buf][(wr * 64 + i * 16 + j) * 32 + qsw];
#pragma unroll
    for (int jj = 0; jj < 4; ++jj)
      bfr[jj] = *(const bf16x8*)&Bs[buf][(wc * 64 + jj * 16 + j) * 32 + qsw];
#pragma unroll
    for (int i = 0; i < 4; ++i)
#pragma unroll
      for (int jj = 0; jj < 4; ++jj)
        acc[i][jj] = __builtin_amdgcn_mfma_f32_16x16x32_bf16(af[i], bfr[jj], acc[i][jj], 0, 0, 0);
    __builtin_amdgcn_s_barrier();        // all waves done reading buf
    __builtin_amdgcn_sched_barrier(0);   // keep re-stage below the barrier
    if (k0 + 64 < Kdim) GEMM_STAGE(k0 + 64, buf);  // overwrite safe now
    buf ^= 1;
  }

  if (MODE == 0) {
#pragma unroll
    for (int jj = 0; jj < 4; ++jj) {
      int col = colBase + wc * 64 + jj * 16 + j;
      int hh = col / 192;
      int rem = col - hh * 192;
      int mm = rem >> 6;   // wave-uniform (16-col runs never cross a 64 boundary)
      int dd = rem & 63;
      float hmv = hm[hh];
      float bv = bias[col];
      float sc = (mm == 0) ? hmv * 0.18033688011112042f : hmv;  // log2(e)/8 folded into Q
#pragma unroll
      for (int i = 0; i < 4; ++i) {
#pragma unroll
        for (int r = 0; r < 4; ++r) {
          int row = rowBase + wr * 64 + i * 16 + quad * 4 + r;
          int n = row >> 11, ss = row & 2047;
          size_t nh = (size_t)(n * 16 + hh);
          float val = (acc[i][jj][r] + bv) * sc;
          if (mm == 0) {
            Qp[nh * 131072 + ss * 64 + dd] = (bf16)val;
          } else if (mm == 1) {
            // lane-local-P Kf: g = ss&127, T = ss>>7,
            // ct = 2*((g>>5)&3) + ((g>>2)&1), i = ((g>>3)&3)*4 + (g&3)
            size_t idx = nh * 131072 + (size_t)(ss >> 7) * 8192 +
                         (size_t)(2 * ((ss >> 5) & 3) + ((ss >> 2) & 1)) * 1024 +
                         (dd >> 5) * 512 + ((dd >> 3) & 3) * 128 +
                         (((ss >> 3) & 3) * 4 + (ss & 3)) * 8 + (dd & 7);
            Kp[idx] = (bf16)val;
          } else {
            // natural fragment-major V: tile (ss>>7), block (kk=(ss>>5)&3, dt=dd>>4),
            // within block quad=(ss>>3)&3, j=dd&15, elem=ss&7
            size_t idx = nh * 131072 + (size_t)(ss >> 7) * 8192 +
                         (((ss >> 5) & 3) * 4 + (dd >> 4)) * 512 +
                         ((ss >> 3) & 3) * 128 + (dd & 15) * 8 + (ss & 7);
            Vp[idx] = (bf16)val;
          }
        }
      }
    }
  } else {
#pragma unroll
    for (int jj = 0; jj < 4; ++jj) {
      int col = colBase + wc * 64 + jj * 16 + j;
      float bv = bias[col];
#pragma unroll
      for (int i = 0; i < 4; ++i)
#pragma unroll
        for (int r = 0; r < 4; ++r) {
          int row = rowBase + wr * 64 + i * 16 + quad * 4 + r;
          outF[(size_t)row * Ncols + col] = acc[i][jj][r] + bv;
        }
    }
  }
}

// ---------------- Flash attention: 64 q-rows/block, grid 1024 --------------
// ROUND-15 CHANGE (completing round-14's variable): round-14 halved LDS to
// 33.8KB (4 blocks/CU capacity) but the grid stayed 512 = 2 blocks/CU --
// capacity never filled (occupancy stayed 33%). Fix: split each q-tile in
// two -> grid 1024 x 512 threads, 64 q-rows/block (each wave ONE 16-row
// tile; rt dimension deleted: qf[2], oacc[4], scalar lrow, pkd[2][2]).
// Now thread-limit (2048/512) AND LDS-limit (160/33.8) both = 4 blocks/CU
// = 32 waves/CU resident. Per-(q,key) math sequence unchanged -> absmax
// unchanged. K/V refetch doubles but is L2-resident (HBM 5%); a head's
// blocks stay on one XCD (b mod 8 = nh mod 8). VGPR <=48 (round-14 level
// with 2x this state); keep __launch_bounds__(512,4) -- no tight cap
// (round-10 lesson). T5 setprio retained.
#define FLASH_STAGE(tileIdx, kOff, vOff)                                    \
  {                                                                         \
    const bf16* kn_ = Kc + (tileIdx) * 2048;                                \
    const bf16* vn_ = Vc + (tileIdx) * 2048;                                \
    int c = ts * 8;                                                         \
    async_ld16(kn_ + c, &KVpool[(kOff) + c]);                               \
    async_ld16(vn_ + c, &KVpool[(vOff) + c]);                               \
  }

#define FLASH_TILE(kOff, vOff)                                              \
  {                                                                         \
    unsigned pkd[2][2];                                                     \
    _Pragma("unroll")                                                       \
    for (int ct = 0; ct < 2; ++ct) {                                        \
      bf16x8 kf0 = *(const bf16x8*)&KVpool[(kOff) + ct * 1024 + lane * 8];  \
      bf16x8 kf1 = *(const bf16x8*)&KVpool[(kOff) + ct * 1024 + 512 + lane * 8]; \
      f32x4 sv = z4;                                                        \
      __builtin_amdgcn_s_setprio(1);                                        \
      sv = __builtin_amdgcn_mfma_f32_16x16x32_bf16(kf0, qf[0], sv, 0, 0, 0);\
      sv = __builtin_amdgcn_mfma_f32_16x16x32_bf16(kf1, qf[1], sv, 0, 0, 0);\
      __builtin_amdgcn_s_setprio(0);                                        \
      float p0 = EXP2F(sv[0]), p1 = EXP2F(sv[1]);                           \
      float p2 = EXP2F(sv[2]), p3 = EXP2F(sv[3]);                           \
      lrow += (p0 + p1) + (p2 + p3);                                        \
      pkd[ct][0] = pack2(p0, p1);                                           \
      pkd[ct][1] = pack2(p2, p3);                                           \
    }                                                                       \
    __builtin_amdgcn_s_setprio(1);                                          \
    {                                                                       \
      union { uint4x u; bf16x8 h; } pa;                                     \
      pa.u = (uint4x){pkd[0][0], pkd[0][1], pkd[1][0], pkd[1][1]};          \
      _Pragma("unroll")                                                     \
      for (int dt = 0; dt < 4; ++dt) {                                      \
        bf16x8 vf = *(const bf16x8*)&KVpool[(vOff) + dt * 512 + lane * 8];  \
        oacc[dt] = __builtin_amdgcn_mfma_f32_16x16x32_bf16(pa.h, vf, oacc[dt], 0, 0, 0); \
      }                                                                     \
    }                                                                       \
    __builtin_amdgcn_s_setprio(0);                                          \
  }

__global__ __launch_bounds__(512, 4) void flash_kernel(const bf16* __restrict__ Qp,
                                                       const bf16* __restrict__ Kf,
                                                       const bf16* __restrict__ Vf,
                                                       bf16* __restrict__ attn) {
  __shared__ bf16 KVpool[16384];     // 32 KB: K bufs [0..8191], V bufs [8192..16383]
  __shared__ float Lsh[8][16];       // per-wave folded l
  const int t = threadIdx.x, lane = t & 63, w = t >> 6;
  const int ts = t & 255;            // thread id within chunk-half
  const int hc = t >> 8;             // chunk (0: waves 0-3, 1: waves 4-7)
  const int j = lane & 15, quad = lane >> 4;
  const int b = blockIdx.x;
  const int qt = b >> 5;             // [0,32)
  const int nh = b & 31;
  const int q0 = qt * 64 + (w & 3) * 16;
  const bf16* Qb = Qp + (size_t)nh * 131072;
  const bf16* Kc = Kf + (size_t)nh * 131072 + hc * 65536;
  const bf16* Vc = Vf + (size_t)nh * 131072 + hc * 65536;

  // pool offsets: K buf b of chunk hc at (hc*2+b)*2048; V at 8192 + same
  const int kb0 = (hc * 2 + 0) * 2048, kb1 = (hc * 2 + 1) * 2048;
  const int vb0 = 8192 + kb0, vb1 = 8192 + kb1;

  bf16x8 qf[2];
#pragma unroll
  for (int kd = 0; kd < 2; ++kd)
    qf[kd] = *(const bf16x8*)&Qb[(size_t)(q0 + j) * 64 + kd * 32 + quad * 8];

  float lrow = 0.f;
  f32x4 oacc[4];
  const f32x4 z4 = {0.f, 0.f, 0.f, 0.f};
#pragma unroll
  for (int dt = 0; dt < 4; ++dt) oacc[dt] = z4;

  // prologue: stage 32-key subtile 0 into buffer 0
  FLASH_STAGE(0, kb0, vb0);

  for (int it2 = 0; it2 < 16; ++it2) {
    __syncthreads();  // drains buf0 staging; all waves done reading buf1
    FLASH_STAGE(it2 * 2 + 1, kb1, vb1);   // overlaps compute below
    FLASH_TILE(kb0, vb0);
    __syncthreads();  // drains buf1 staging; all waves done reading buf0
    if (it2 < 15) FLASH_STAGE(it2 * 2 + 2, kb0, vb0);
    FLASH_TILE(kb1, vb1);
  }

  // ---- in-block chunk merge ----
  // fold l across quads: lane (0,j) holds l for q = q0 + j
  float lf = lrow;
  lf += __shfl_xor(lf, 16);
  lf += __shfl_xor(lf, 32);
  __syncthreads();  // all waves done with KVpool -> safe to overlay Osh
  if (quad == 0) Lsh[w][j] = lf;
  float* Osh = (float*)&KVpool[0];  // 16 KB = 4 waves x 4dt x 4r x 64
  if (w >= 4) {
    int wb = w - 4;
#pragma unroll
    for (int dt = 0; dt < 4; ++dt)
#pragma unroll
      for (int r = 0; r < 4; ++r)
        Osh[(((wb * 4 + dt) * 4) + r) * 64 + lane] = oacc[dt][r];
  }
  __syncthreads();  // Osh + Lsh visible
  if (w < 4) {
    int n = nh >> 4, h = nh & 15;
    float inv[4];
#pragma unroll
    for (int r = 0; r < 4; ++r) {
      int idx = quad * 4 + r;
      inv[r] = 1.0f / (Lsh[w][idx] + Lsh[w + 4][idx]);
    }
#pragma unroll
    for (int r = 0; r < 4; ++r) {
      int s = q0 + quad * 4 + r;
      size_t base = ((size_t)(n * 2048 + s)) * 1024 + h * 64;
#pragma unroll
      for (int dt = 0; dt < 4; ++dt) {
        float o = oacc[dt][r] + Osh[(((w * 4 + dt) * 4) + r) * 64 + lane];
        attn[base + dt * 16 + j] = (bf16)(o * inv[r]);
      }
    }
  }
}

extern "C" void kernel_launch(void* const* d_in, const int* in_sizes, int n_in,
                              void* d_out, int out_size, void* d_ws, size_t ws_size,
                              hipStream_t stream) {
  const float* x = (const float*)d_in[0];
  const float* head_mask = (const float*)d_in[1];
  const float* qkv_w = (const float*)d_in[2];
  const float* qkv_b = (const float*)d_in[3];
  const float* fc_w = (const float*)d_in[4];
  const float* fc_b = (const float*)d_in[5];
  float* out = (float*)d_out;

  char* ws = (char*)d_ws;
  bf16* x_bf    = (bf16*)(ws + 0);                    // 8 MB (later reused as attn)
  bf16* qkvw_bf = (bf16*)(ws + ((size_t)8 << 20));    // 6 MB
  bf16* fcw_bf  = (bf16*)(ws + ((size_t)14 << 20));   // 2 MB
  bf16* Qp      = (bf16*)(ws + ((size_t)16 << 20));   // 8 MB
  bf16* Kf      = (bf16*)(ws + ((size_t)24 << 20));   // 8 MB (fragment-major K, lane-local-P perm)
  bf16* Vf      = (bf16*)(ws + ((size_t)32 << 20));   // 8 MB (fragment-major V, natural order)
  bf16* attn = x_bf;              // x_bf dead after gemm1

  cvt3_kernel<<<8192, 256, 0, stream>>>(x, qkv_w, fc_w, x_bf, qkvw_bf, fcw_bf);
  gemm_bt_kernel<0><<<32 * 24, 256, 0, stream>>>(x_bf, qkvw_bf, qkv_b, head_mask,
                                                 Qp, Kf, Vf, nullptr, 3072, 1024, 32);
  flash_kernel<<<1024, 512, 0, stream>>>(Qp, Kf, Vf, attn);
  gemm_bt_kernel<1><<<32 * 8, 256, 0, stream>>>(attn, fcw_bf, fc_b, nullptr,
                                                nullptr, nullptr, nullptr, out, 1024, 1024, 32);
}

// Round 16
// 185.079 us; speedup vs baseline: 1.0205x; 1.0205x over previous
//
#include <hip/hip_runtime.h>
#include <hip/hip_bf16.h>

typedef __bf16 bf16;
typedef __attribute__((ext_vector_type(8))) __bf16 bf16x8;
typedef __attribute__((ext_vector_type(4))) __bf16 bf16x4;
typedef __attribute__((ext_vector_type(4))) float f32x4;
typedef __attribute__((ext_vector_type(4))) unsigned int uint4x;

#if __has_builtin(__builtin_amdgcn_exp2f)
#define EXP2F(x) __builtin_amdgcn_exp2f(x)
#else
#define EXP2F(x) exp2f(x)
#endif

#define AS1 __attribute__((address_space(1)))
#define AS3 __attribute__((address_space(3)))

static __device__ __forceinline__ void async_ld16(const bf16* g, bf16* l) {
  __builtin_amdgcn_global_load_lds((const AS1 void*)g, (AS3 void*)l, 16, 0, 0);
}

// f32 -> bf16 with EXPLICIT round-to-nearest-even bit arithmetic (proven in
// round 4: cvt_pk-based paths failed at ~9e-3; this passes at 2.4e-3).
// Valid for positive finite inputs (exp2 output); no NaN handling needed.
static __device__ __forceinline__ unsigned bf16rne(float x) {
  unsigned u = __float_as_uint(x);
  return (u + 0x7fffu + ((u >> 16) & 1u)) >> 16;
}
static __device__ __forceinline__ unsigned pack2(float a, float b) {
  return bf16rne(a) | (bf16rne(b) << 16);
}

// ---------------- fused fp32 -> bf16 conversion (x, qkv_w, fc_w) ----------
__global__ void cvt3_kernel(const float* __restrict__ x, const float* __restrict__ qw,
                            const float* __restrict__ fw, bf16* __restrict__ xb,
                            bf16* __restrict__ qwb, bf16* __restrict__ fwb) {
  int b = blockIdx.x;
  const float* src;
  bf16* dst;
  int i;
  if (b < 4096) { src = x; dst = xb; i = b * 256 + threadIdx.x; }
  else if (b < 7168) { src = qw; dst = qwb; i = (b - 4096) * 256 + threadIdx.x; }
  else { src = fw; dst = fwb; i = (b - 7168) * 256 + threadIdx.x; }
  f32x4 v = *(const f32x4*)(src + (size_t)i * 4);
  bf16x4 o;
  o[0] = (bf16)v[0]; o[1] = (bf16)v[1]; o[2] = (bf16)v[2]; o[3] = (bf16)v[3];
  *(bf16x4*)(dst + (size_t)i * 4) = o;
}

// ---------------- BT-GEMM: C[M,N] = A[M,K] @ B[N,K]^T ----------------
// (byte-identical to the passing rounds 13/14: T4 counted-vmcnt + raw
// s_barrier distance-2 K-loop, T2 pre-swizzled-source XOR fragment reads.)
// MODE 0 epilogue: bias + head_mask; Q -> [nh][s][d] (x log2(e)/8);
//   K -> fragment-major Kf with the LANE-LOCAL-P permutation baked in
//     (key g at C-tile ct = 2*(g>>5)+((g>>2)&1), row i = ((g>>3)&3)*4+(g&3));
//   V -> natural fragment-major Vf. Both key-linear at 32-key granularity.
// MODE 1: fp32 out = acc + bias.
#define GEMM_STAGE(k0_, buf_)                                                    \
  {                                                                              \
    async_ld16(A + (size_t)(rowBase + r0) * Kdim + (k0_) + csw, &As[buf_][f0]);  \
    async_ld16(A + (size_t)(rowBase + r1) * Kdim + (k0_) + csw, &As[buf_][f1]);  \
    async_ld16(Bw + (size_t)(colBase + r0) * Kdim + (k0_) + csw, &Bs[buf_][f0]); \
    async_ld16(Bw + (size_t)(colBase + r1) * Kdim + (k0_) + csw, &Bs[buf_][f1]); \
  }

template <int MODE>
__global__ __launch_bounds__(256, 2) void gemm_bt_kernel(
    const bf16* __restrict__ A, const bf16* __restrict__ Bw,
    const float* __restrict__ bias, const float* __restrict__ hm,
    bf16* __restrict__ Qp, bf16* __restrict__ Kp, bf16* __restrict__ Vp,
    float* __restrict__ outF, int Ncols, int Kdim, int rowBlkCount) {
  __shared__ bf16 As[2][128 * 32];
  __shared__ bf16 Bs[2][128 * 32];
  const int t = threadIdx.x, lane = t & 63, w = t >> 6;
  const int wr = w >> 1, wc = w & 1;
  const int j = lane & 15, quad = lane >> 4;
  const int rowBlk = blockIdx.x % rowBlkCount;
  const int colBlk = blockIdx.x / rowBlkCount;
  const int rowBase = rowBlk * 128, colBase = colBlk * 128;

  f32x4 acc[4][4];
  const f32x4 z4 = {0.f, 0.f, 0.f, 0.f};
#pragma unroll
  for (int i = 0; i < 4; ++i)
#pragma unroll
    for (int jj = 0; jj < 4; ++jj) acc[i][jj] = z4;

  const int f0 = t * 8;
  const int f1 = f0 + 2048;
  const int r0 = f0 >> 5, r1 = r0 + 64;
  const int csw = (((t & 3) ^ ((r0 >> 1) & 3))) * 8;
  const int qsw = (quad ^ ((j >> 1) & 3)) * 8;

  // distance-2 prologue: tiles 0 and 1 in flight (8 loads/thread)
  GEMM_STAGE(0, 0);
  if (32 < Kdim) GEMM_STAGE(32, 1);
  int buf = 0;
  for (int k0 = 0; k0 < Kdim; k0 += 32) {
    // wait only THIS tile's 4 loads (oldest); next tile's stay in flight
    if (k0 + 32 < Kdim) {
      asm volatile("s_waitcnt vmcnt(4)" ::: "memory");
    } else {
      asm volatile("s_waitcnt vmcnt(0)" ::: "memory");
    }
    __builtin_amdgcn_s_barrier();        // all waves' tile loads complete
    __builtin_amdgcn_sched_barrier(0);   // rule #18: pin ds_reads after wait
    bf16x8 af[4], bfr[4];
#pragma unroll
    for (int i = 0; i < 4; ++i)
      af[i] = *(const bf16x8*)&As[buf][(wr * 64 + i * 16 + j) * 32 + qsw];
#pragma unroll
    for (int jj = 0; jj < 4; ++jj)
      bfr[jj] = *(const bf16x8*)&Bs[buf][(wc * 64 + jj * 16 + j) * 32 + qsw];
#pragma unroll
    for (int i = 0; i < 4; ++i)
#pragma unroll
      for (int jj = 0; jj < 4; ++jj)
        acc[i][jj] = __builtin_amdgcn_mfma_f32_16x16x32_bf16(af[i], bfr[jj], acc[i][jj], 0, 0, 0);
    __builtin_amdgcn_s_barrier();        // all waves done reading buf
    __builtin_amdgcn_sched_barrier(0);   // keep re-stage below the barrier
    if (k0 + 64 < Kdim) GEMM_STAGE(k0 + 64, buf);  // overwrite safe now
    buf ^= 1;
  }

  if (MODE == 0) {
#pragma unroll
    for (int jj = 0; jj < 4; ++jj) {
      int col = colBase + wc * 64 + jj * 16 + j;
      int hh = col / 192;
      int rem = col - hh * 192;
      int mm = rem >> 6;   // wave-uniform (16-col runs never cross a 64 boundary)
      int dd = rem & 63;
      float hmv = hm[hh];
      float bv = bias[col];
      float sc = (mm == 0) ? hmv * 0.18033688011112042f : hmv;  // log2(e)/8 folded into Q
#pragma unroll
      for (int i = 0; i < 4; ++i) {
#pragma unroll
        for (int r = 0; r < 4; ++r) {
          int row = rowBase + wr * 64 + i * 16 + quad * 4 + r;
          int n = row >> 11, ss = row & 2047;
          size_t nh = (size_t)(n * 16 + hh);
          float val = (acc[i][jj][r] + bv) * sc;
          if (mm == 0) {
            Qp[nh * 131072 + ss * 64 + dd] = (bf16)val;
          } else if (mm == 1) {
            // lane-local-P Kf: g = ss&127, T = ss>>7,
            // ct = 2*((g>>5)&3) + ((g>>2)&1), i = ((g>>3)&3)*4 + (g&3)
            size_t idx = nh * 131072 + (size_t)(ss >> 7) * 8192 +
                         (size_t)(2 * ((ss >> 5) & 3) + ((ss >> 2) & 1)) * 1024 +
                         (dd >> 5) * 512 + ((dd >> 3) & 3) * 128 +
                         (((ss >> 3) & 3) * 4 + (ss & 3)) * 8 + (dd & 7);
            Kp[idx] = (bf16)val;
          } else {
            // natural fragment-major V: tile (ss>>7), block (kk=(ss>>5)&3, dt=dd>>4),
            // within block quad=(ss>>3)&3, j=dd&15, elem=ss&7
            size_t idx = nh * 131072 + (size_t)(ss >> 7) * 8192 +
                         (((ss >> 5) & 3) * 4 + (dd >> 4)) * 512 +
                         ((ss >> 3) & 3) * 128 + (dd & 15) * 8 + (ss & 7);
            Vp[idx] = (bf16)val;
          }
        }
      }
    }
  } else {
#pragma unroll
    for (int jj = 0; jj < 4; ++jj) {
      int col = colBase + wc * 64 + jj * 16 + j;
      float bv = bias[col];
#pragma unroll
      for (int i = 0; i < 4; ++i)
#pragma unroll
        for (int r = 0; r < 4; ++r) {
          int row = rowBase + wr * 64 + i * 16 + quad * 4 + r;
          outF[(size_t)row * Ncols + col] = acc[i][jj][r] + bv;
        }
    }
  }
}

// ---------------- Flash attention: r14 structure + T4 counted-vmcnt --------
// ROUND-16: r15 post-mortem -- doubling occupancy (33->58%) with rt=1 made
// flash SLOWER (52.5->55.0): rt=1 halves q-rows/wave, doubling LDS ds_read
// traffic (1.07->2.1 GB, ~40us LDS-pipe floor). Wave-starvation theory dead.
// REVERT to r14 (rt=2, 32-key subtiles, grid 512, 2 blocks/CU, best 52.5us)
// and apply the ONE proven lever it lacks: T4 counted-vmcnt (the round-13
// gemm win, 57.2 -> <53.6us). Flash still used __syncthreads = vmcnt(0)
// drain at every barrier. New loop mirrors the verified gemm pattern:
// distance-2 staging; per half-iteration {vmcnt(2); s_barrier;
// sched_barrier(0); TILE; s_barrier; sched_barrier(0); stage(t+2)}.
// Ledger (2 loads/thread/stage): 4 in flight at each wait, wait oldest 2;
// final wait vmcnt(0). Read-before-staged guarded by wait+barrier;
// write-before-read safe (ds_read results register-resident before 2nd
// barrier via lgkm data-dependence). Values bit-identical -> absmax same.
#define FLASH_STAGE(tileIdx, kOff, vOff)                                    \
  {                                                                         \
    const bf16* kn_ = Kc + (tileIdx) * 2048;                                \
    const bf16* vn_ = Vc + (tileIdx) * 2048;                                \
    int c = ts * 8;                                                         \
    async_ld16(kn_ + c, &KVpool[(kOff) + c]);                               \
    async_ld16(vn_ + c, &KVpool[(vOff) + c]);                               \
  }

#define FLASH_TILE(kOff, vOff)                                              \
  {                                                                         \
    unsigned pkd[2][2][2];                                                  \
    _Pragma("unroll")                                                       \
    for (int ct = 0; ct < 2; ++ct) {                                        \
      bf16x8 kf0 = *(const bf16x8*)&KVpool[(kOff) + ct * 1024 + lane * 8];  \
      bf16x8 kf1 = *(const bf16x8*)&KVpool[(kOff) + ct * 1024 + 512 + lane * 8]; \
      _Pragma("unroll")                                                     \
      for (int rt = 0; rt < 2; ++rt) {                                      \
        f32x4 sv = z4;                                                      \
        __builtin_amdgcn_s_setprio(1);                                      \
        sv = __builtin_amdgcn_mfma_f32_16x16x32_bf16(kf0, qf[rt][0], sv, 0, 0, 0); \
        sv = __builtin_amdgcn_mfma_f32_16x16x32_bf16(kf1, qf[rt][1], sv, 0, 0, 0); \
        __builtin_amdgcn_s_setprio(0);                                      \
        float p0 = EXP2F(sv[0]), p1 = EXP2F(sv[1]);                         \
        float p2 = EXP2F(sv[2]), p3 = EXP2F(sv[3]);                         \
        lrow[rt] += (p0 + p1) + (p2 + p3);                                  \
        pkd[rt][ct][0] = pack2(p0, p1);                                     \
        pkd[rt][ct][1] = pack2(p2, p3);                                     \
      }                                                                     \
    }                                                                       \
    __builtin_amdgcn_s_setprio(1);                                          \
    {                                                                       \
      union { uint4x u; bf16x8 h; } pa[2];                                  \
      _Pragma("unroll")                                                     \
      for (int rt = 0; rt < 2; ++rt)                                        \
        pa[rt].u = (uint4x){pkd[rt][0][0], pkd[rt][0][1],                   \
                            pkd[rt][1][0], pkd[rt][1][1]};                  \
      _Pragma("unroll")                                                     \
      for (int dt = 0; dt < 4; ++dt) {                                      \
        bf16x8 vf = *(const bf16x8*)&KVpool[(vOff) + dt * 512 + lane * 8];  \
        oacc[0][dt] = __builtin_amdgcn_mfma_f32_16x16x32_bf16(pa[0].h, vf, oacc[0][dt], 0, 0, 0); \
        oacc[1][dt] = __builtin_amdgcn_mfma_f32_16x16x32_bf16(pa[1].h, vf, oacc[1][dt], 0, 0, 0); \
      }                                                                     \
    }                                                                       \
    __builtin_amdgcn_s_setprio(0);                                          \
  }

__global__ __launch_bounds__(512, 4) void flash_kernel(const bf16* __restrict__ Qp,
                                                       const bf16* __restrict__ Kf,
                                                       const bf16* __restrict__ Vf,
                                                       bf16* __restrict__ attn) {
  __shared__ bf16 KVpool[16384];     // 32 KB: K bufs [0..8191], V bufs [8192..16383]
  __shared__ float Lsh[8][32];       // per-wave folded l  1 KB
  const int t = threadIdx.x, lane = t & 63, w = t >> 6;
  const int ts = t & 255;            // thread id within chunk-half
  const int hc = t >> 8;             // chunk (0: waves 0-3, 1: waves 4-7)
  const int j = lane & 15, quad = lane >> 4;
  const int b = blockIdx.x;
  const int qt = b >> 5;             // [0,16)
  const int nh = b & 31;
  const int q0 = qt * 128 + (w & 3) * 32;
  const bf16* Qb = Qp + (size_t)nh * 131072;
  const bf16* Kc = Kf + (size_t)nh * 131072 + hc * 65536;
  const bf16* Vc = Vf + (size_t)nh * 131072 + hc * 65536;

  // pool offsets: K buf b of chunk hc at (hc*2+b)*2048; V at 8192 + same
  const int kb0 = (hc * 2 + 0) * 2048, kb1 = (hc * 2 + 1) * 2048;
  const int vb0 = 8192 + kb0, vb1 = 8192 + kb1;

  bf16x8 qf[2][2];
#pragma unroll
  for (int rt = 0; rt < 2; ++rt)
#pragma unroll
    for (int kd = 0; kd < 2; ++kd)
      qf[rt][kd] = *(const bf16x8*)&Qb[(size_t)(q0 + rt * 16 + j) * 64 + kd * 32 + quad * 8];

  float lrow[2] = {0.f, 0.f};
  f32x4 oacc[2][4];
  const f32x4 z4 = {0.f, 0.f, 0.f, 0.f};
#pragma unroll
  for (int rt = 0; rt < 2; ++rt)
#pragma unroll
    for (int dt = 0; dt < 4; ++dt) oacc[rt][dt] = z4;

  // T4 distance-2 prologue: subtiles 0 and 1 in flight (4 loads/thread)
  FLASH_STAGE(0, kb0, vb0);
  FLASH_STAGE(1, kb1, vb1);

  for (int it2 = 0; it2 < 16; ++it2) {
    // wait only buf0's 2 loads (oldest); buf1's ride across the barrier
    asm volatile("s_waitcnt vmcnt(2)" ::: "memory");
    __builtin_amdgcn_s_barrier();
    __builtin_amdgcn_sched_barrier(0);
    FLASH_TILE(kb0, vb0);
    __builtin_amdgcn_s_barrier();        // all waves done reading buf0
    __builtin_amdgcn_sched_barrier(0);
    if (it2 * 2 + 2 < 32) FLASH_STAGE(it2 * 2 + 2, kb0, vb0);
    if (it2 < 15) {
      asm volatile("s_waitcnt vmcnt(2)" ::: "memory");
    } else {
      asm volatile("s_waitcnt vmcnt(0)" ::: "memory");
    }
    __builtin_amdgcn_s_barrier();
    __builtin_amdgcn_sched_barrier(0);
    FLASH_TILE(kb1, vb1);
    __builtin_amdgcn_s_barrier();        // all waves done reading buf1
    __builtin_amdgcn_sched_barrier(0);
    if (it2 * 2 + 3 < 32) FLASH_STAGE(it2 * 2 + 3, kb1, vb1);
  }

  // ---- in-block chunk merge ----
  // fold l across quads: lane (0,j) holds l for q = q0 + rt*16 + j
  float lf[2];
#pragma unroll
  for (int rt = 0; rt < 2; ++rt) {
    float l = lrow[rt];
    l += __shfl_xor(l, 16);
    l += __shfl_xor(l, 32);
    lf[rt] = l;
  }
  __syncthreads();  // all waves done with KVpool -> safe to overlay Osh
  if (quad == 0) {
    Lsh[w][j] = lf[0];
    Lsh[w][16 + j] = lf[1];
  }
  float* Osh = (float*)&KVpool[0];  // 32 KB = 4 waves x 2rt x 4dt x 4r x 64
  if (w >= 4) {
    int wb = w - 4;
#pragma unroll
    for (int rt = 0; rt < 2; ++rt)
#pragma unroll
      for (int dt = 0; dt < 4; ++dt)
#pragma unroll
        for (int r = 0; r < 4; ++r)
          Osh[((((wb * 2 + rt) * 4 + dt) * 4) + r) * 64 + lane] = oacc[rt][dt][r];
  }
  __syncthreads();  // Osh + Lsh visible
  if (w < 4) {
    int n = nh >> 4, h = nh & 15;
    float inv[2][4];
#pragma unroll
    for (int rt = 0; rt < 2; ++rt)
#pragma unroll
      for (int r = 0; r < 4; ++r) {
        int idx = rt * 16 + quad * 4 + r;
        inv[rt][r] = 1.0f / (Lsh[w][idx] + Lsh[w + 4][idx]);
      }
#pragma unroll
    for (int rt = 0; rt < 2; ++rt)
#pragma unroll
      for (int r = 0; r < 4; ++r) {
        int s = q0 + rt * 16 + quad * 4 + r;
        size_t base = ((size_t)(n * 2048 + s)) * 1024 + h * 64;
#pragma unroll
        for (int dt = 0; dt < 4; ++dt) {
          float o = oacc[rt][dt][r] +
                    Osh[((((w * 2 + rt) * 4 + dt) * 4) + r) * 64 + lane];
          attn[base + dt * 16 + j] = (bf16)(o * inv[rt][r]);
        }
      }
  }
}

extern "C" void kernel_launch(void* const* d_in, const int* in_sizes, int n_in,
                              void* d_out, int out_size, void* d_ws, size_t ws_size,
                              hipStream_t stream) {
  const float* x = (const float*)d_in[0];
  const float* head_mask = (const float*)d_in[1];
  const float* qkv_w = (const float*)d_in[2];
  const float* qkv_b = (const float*)d_in[3];
  const float* fc_w = (const float*)d_in[4];
  const float* fc_b = (const float*)d_in[5];
  float* out = (float*)d_out;

  char* ws = (char*)d_ws;
  bf16* x_bf    = (bf16*)(ws + 0);                    // 8 MB (later reused as attn)
  bf16* qkvw_bf = (bf16*)(ws + ((size_t)8 << 20));    // 6 MB
  bf16* fcw_bf  = (bf16*)(ws + ((size_t)14 << 20));   // 2 MB
  bf16* Qp      = (bf16*)(ws + ((size_t)16 << 20));   // 8 MB
  bf16* Kf      = (bf16*)(ws + ((size_t)24 << 20));   // 8 MB (fragment-major K, lane-local-P perm)
  bf16* Vf      = (bf16*)(ws + ((size_t)32 << 20));   // 8 MB (fragment-major V, natural order)
  bf16* attn = x_bf;              // x_bf dead after gemm1

  cvt3_kernel<<<8192, 256, 0, stream>>>(x, qkv_w, fc_w, x_bf, qkvw_bf, fcw_bf);
  gemm_bt_kernel<0><<<32 * 24, 256, 0, stream>>>(x_bf, qkvw_bf, qkv_b, head_mask,
                                                 Qp, Kf, Vf, nullptr, 3072, 1024, 32);
  flash_kernel<<<512, 512, 0, stream>>>(Qp, Kf, Vf, attn);
  gemm_bt_kernel<1><<<32 * 8, 256, 0, stream>>>(attn, fcw_bf, fc_b, nullptr,
                                                nullptr, nullptr, nullptr, out, 1024, 1024, 32);
}